// Round 8
// baseline (1552.485 us; speedup 1.0000x reference)
//
#include <hip/hip_runtime.h>
#include <hip/hip_fp16.h>
#include <math.h>

// ---------------------------------------------------------------------------
// ChebConv GNN. N=100000, E=1600000, D=64, K=5, 3 residual blocks.
// Round 8:
//  - Uniform-pair prop: wave = 1 node, lane = channel (2B fp16 gather,
//    128B/instr). (idx,w) pairs are wave-uniform loads -> ZERO shuffles,
//    exact ceil(deg/8) trip count, zero-padded batches (pair buffer memset
//    once per launch so pad slots contribute w=0).
//  - All activations fp16; MFMA GEMMs (v_mfma_f32_16x16x32_f16).
//  - Padded CSR (PSTR=48), one atomic per edge.
// ---------------------------------------------------------------------------

#define PSTR 48

typedef _Float16 f16x8 __attribute__((ext_vector_type(8)));
typedef float f32x4 __attribute__((ext_vector_type(4)));

__device__ __forceinline__ float gelu_f(float v) {
  return 0.5f * v * (1.0f + erff(v * 0.70710678118654752440f));
}

__global__ __launch_bounds__(256) void k_deg(const int* __restrict__ src,
                                             const float* __restrict__ ea,
                                             float* __restrict__ deg, int E) {
  int e = blockIdx.x * 256 + threadIdx.x;
  if (e < E) atomicAdd(&deg[src[e]], ea[e]);
}

__global__ __launch_bounds__(256) void k_dis(float* __restrict__ deg, int n) {
  int i = blockIdx.x * 256 + threadIdx.x;
  if (i < n) {
    float d = deg[i];
    deg[i] = (d > 0.f) ? rsqrtf(d) : 0.f;
  }
}

__global__ __launch_bounds__(256) void k_fill(
    const int* __restrict__ src, const int* __restrict__ tgt,
    const float* __restrict__ ea, const float* __restrict__ dis,
    int* __restrict__ cur, unsigned long long* __restrict__ pair, int E) {
  int e = blockIdx.x * 256 + threadIdx.x;
  if (e < E) {
    int s = src[e], t = tgt[e];
    int pos = atomicAdd(&cur[t], 1);
    if (pos < PSTR) {
      float w = -ea[e] * dis[s] * dis[t];
      unsigned long long v =
          (unsigned long long)(unsigned int)s |
          ((unsigned long long)__float_as_uint(w) << 32);
      pair[(size_t)t * PSTR + pos] = v;
    }
  }
}

// ---- encoder: h16 = gelu(gelu(x@w1+b1)@w2+b2) ----
__global__ __launch_bounds__(256) void k_encode(
    const float* __restrict__ x, const float* __restrict__ w1,
    const float* __restrict__ b1, const float* __restrict__ w2,
    const float* __restrict__ b2, __half* __restrict__ h16, int n) {
  __shared__ float sw1[4 * 64];
  __shared__ float sb1[64];
  __shared__ float sw2[64 * 64];
  __shared__ float sb2[64];
  __shared__ float smid[4][64];
  if (threadIdx.x < 256) sw1[threadIdx.x] = w1[threadIdx.x];
  if (threadIdx.x < 64) {
    sb1[threadIdx.x] = b1[threadIdx.x];
    sb2[threadIdx.x] = b2[threadIdx.x];
  }
  for (int i = threadIdx.x; i < 4096; i += 256) sw2[i] = w2[i];
  __syncthreads();
  const int wave = threadIdx.x >> 6;
  const int lane = threadIdx.x & 63;
  for (int base = blockIdx.x * 4; base < n; base += gridDim.x * 4) {
    const int node = base + wave;
    const bool ok = node < n;
    float m = 0.f;
    if (ok) {
      const float4 xv = *(const float4*)(x + (size_t)node * 4);
      m = xv.x * sw1[lane] + xv.y * sw1[64 + lane] + xv.z * sw1[128 + lane] +
          xv.w * sw1[192 + lane] + sb1[lane];
      m = gelu_f(m);
    }
    smid[wave][lane] = m;
    __syncthreads();
    float o = sb2[lane];
#pragma unroll 8
    for (int k = 0; k < 64; ++k) o += smid[wave][k] * sw2[k * 64 + lane];
    if (ok) h16[(size_t)node * 64 + lane] = __float2half_rn(gelu_f(o));
    __syncthreads();
  }
}

// ---- prop: out16 = [2*]segsum(fp16 gather)[- prev16]; wave = 1 node -------
// lane = channel. (idx,w) pair row is wave-uniform: plain loads, no shuffle.
// Batches of 8 edges; pad slots are zero (w=0, idx=0) -> contribute nothing.
template <bool HASPREV>
__global__ __launch_bounds__(256) void k_prop(
    const __half* __restrict__ hin16, const int* __restrict__ cnt,
    const unsigned long long* __restrict__ pair,
    const __half* __restrict__ prev16, __half* __restrict__ out16, int n) {
  const int node = (int)((blockIdx.x * 256 + threadIdx.x) >> 6);
  const int lane = threadIdx.x & 63;
  if (node >= n) return;
  const int deg = min(cnt[node], PSTR);
  const unsigned long long* __restrict__ prow = pair + (size_t)node * PSTR;
  float acc = 0.f;
  for (int j = 0; j < deg; j += 8) {
    unsigned long long p0 = prow[j + 0];
    unsigned long long p1 = prow[j + 1];
    unsigned long long p2 = prow[j + 2];
    unsigned long long p3 = prow[j + 3];
    unsigned long long p4 = prow[j + 4];
    unsigned long long p5 = prow[j + 5];
    unsigned long long p6 = prow[j + 6];
    unsigned long long p7 = prow[j + 7];
#define EDGE(P)                                                       \
  {                                                                   \
    const int idx_ = (int)(unsigned int)(P);                          \
    const float w_ = __uint_as_float((unsigned int)((P) >> 32));      \
    acc = fmaf(w_, __half2float(hin16[((size_t)idx_ << 6) + lane]),   \
               acc);                                                  \
  }
    EDGE(p0) EDGE(p1) EDGE(p2) EDGE(p3)
    EDGE(p4) EDGE(p5) EDGE(p6) EDGE(p7)
#undef EDGE
  }
  float r = acc;
  if (HASPREV)
    r = 2.f * acc - __half2float(prev16[((size_t)node << 6) + lane]);
  out16[((size_t)node << 6) + lane] = __float2half_rn(r);
}

// ---- MFMA multi-buffer GEMM -------------------------------------------------
// out16 = gelu(sum_{b<5} A_b @ W_b [+ Aex@Wex] + bias1 [+ bias2]).
// A_0=A0, A_b=Atx+(b-1)*n64. All A fp16 row-major [n][64]. W fp32 in global,
// staged fp16 in LDS pre-swizzled to b-frag order.
// Fragments (mfma_f32_16x16x32_f16): a: A[lane&15][8*(lane>>4)+j] (+k0);
// b: W[k0+8*(lane>>4)+j][col=lane&15(+16*ct)]; d: row=4*(lane>>4)+j, col=lane&15.
// 512 threads = 8 waves; wave w -> rows blk*128 + w*16 .. +15.
template <int TOT, bool HASEX, bool GELU>
__global__ __launch_bounds__(512) void k_gemm_mfma(
    const __half* __restrict__ A0, const __half* __restrict__ Atx,
    const float* __restrict__ Wb, const __half* __restrict__ Aex,
    const float* __restrict__ Wex, const float* __restrict__ bias1,
    const float* __restrict__ bias2, __half* __restrict__ out16, int n) {
  __shared__ __align__(16) _Float16 sWh[TOT * 2 * 4 * 64 * 8];
  const int tid = threadIdx.x;
  for (int b = 0; b < TOT; ++b) {
    const float* Wp = (b < 5) ? Wb + b * 4096 : Wex;
    for (int idx = tid; idx < 4096; idx += 512) {
      const int k = idx >> 6, nn = idx & 63;
      const int lane = (nn & 15) | (((k >> 3) & 3) << 4);
      const int dst =
          (((b * 2 + (k >> 5)) * 4 + (nn >> 4)) * 64 + lane) * 8 + (k & 7);
      sWh[dst] = (_Float16)Wp[idx];
    }
  }
  __syncthreads();

  const int wv = tid >> 6;
  const int lane = tid & 63;
  const int kg = lane >> 4;  // 0..3
  const int row = blockIdx.x * 128 + wv * 16 + (lane & 15);
  const bool rok = row < n;
  const size_t n64 = (size_t)n * 64;
  const f16x8* bw = (const f16x8*)sWh;

  f32x4 acc[4];
#pragma unroll
  for (int ct = 0; ct < 4; ++ct) acc[ct] = (f32x4){0.f, 0.f, 0.f, 0.f};

  for (int b = 0; b < TOT; ++b) {
    const __half* Ap =
        (b == 0) ? A0 : (b < 5 ? Atx + (size_t)(b - 1) * n64 : Aex);
    f16x8 a0 = {}, a1 = {};
    if (rok) {
      a0 = *(const f16x8*)(Ap + (size_t)row * 64 + kg * 8);
      a1 = *(const f16x8*)(Ap + (size_t)row * 64 + 32 + kg * 8);
    }
#pragma unroll
    for (int ct = 0; ct < 4; ++ct) {
      const f16x8 b0 = bw[((b * 2 + 0) * 4 + ct) * 64 + lane];
      const f16x8 b1 = bw[((b * 2 + 1) * 4 + ct) * 64 + lane];
      acc[ct] = __builtin_amdgcn_mfma_f32_16x16x32_f16(a0, b0, acc[ct], 0, 0, 0);
      acc[ct] = __builtin_amdgcn_mfma_f32_16x16x32_f16(a1, b1, acc[ct], 0, 0, 0);
    }
  }

  const int orow0 = blockIdx.x * 128 + wv * 16 + (lane >> 4) * 4;
#pragma unroll
  for (int ct = 0; ct < 4; ++ct) {
    const int col = ct * 16 + (lane & 15);
    float bb = bias1[col];
    if (HASEX) bb += bias2[col];
#pragma unroll
    for (int j = 0; j < 4; ++j) {
      const int r = orow0 + j;
      if (r < n) {
        float v = acc[ct][j] + bb;
        if (GELU) v = gelu_f(v);
        out16[(size_t)r * 64 + col] = __float2half_rn(v);
      }
    }
  }
}

// ---- decoder: out[n] = gelu(dot(h16[n], d1w) + d1b)*d2w + d2b ----
__global__ __launch_bounds__(256) void k_decode(
    const __half* __restrict__ h16, const float* __restrict__ d1w,
    const float* __restrict__ d1b, const float* __restrict__ d2w,
    const float* __restrict__ d2b, float* __restrict__ out, int n) {
  const int q = (blockIdx.x * 256 + threadIdx.x) >> 4;  // node
  const int l = threadIdx.x & 15;
  if (q >= n) return;
  union { short4 s; __half2 h[2]; } u;
  u.s = *(const short4*)(h16 + (size_t)q * 64 + l * 4);
  const float2 v01 = __half22float2(u.h[0]);
  const float2 v23 = __half22float2(u.h[1]);
  const float4 w = *(const float4*)(d1w + l * 4);
  float s = v01.x * w.x + v01.y * w.y + v23.x * w.z + v23.y * w.w;
  s += __shfl_xor(s, 1, 64);
  s += __shfl_xor(s, 2, 64);
  s += __shfl_xor(s, 4, 64);
  s += __shfl_xor(s, 8, 64);
  if (l == 0) out[q] = gelu_f(s + d1b[0]) * d2w[0] + d2b[0];
}

extern "C" void kernel_launch(void* const* d_in, const int* in_sizes, int n_in,
                              void* d_out, int out_size, void* d_ws,
                              size_t ws_size, hipStream_t stream) {
  const float* x = (const float*)d_in[0];
  const int* ei = (const int*)d_in[1];
  const float* ea = (const float*)d_in[2];
  const float* e1w = (const float*)d_in[3];
  const float* e1b = (const float*)d_in[4];
  const float* e2w = (const float*)d_in[5];
  const float* e2b = (const float*)d_in[6];
  const float* cw1 = (const float*)d_in[7];
  const float* cb1 = (const float*)d_in[8];
  const float* cw2 = (const float*)d_in[9];
  const float* cb2 = (const float*)d_in[10];
  const float* lw = (const float*)d_in[11];
  const float* lb = (const float*)d_in[12];
  const float* d1w = (const float*)d_in[13];
  const float* d1b = (const float*)d_in[14];
  const float* d2w = (const float*)d_in[15];
  const float* d2b = (const float*)d_in[16];

  const int N = in_sizes[0] / 4;
  const int E = in_sizes[2];
  const int* src = ei;
  const int* tgt = ei + E;

  char* p = (char*)d_ws;
  auto carve = [&](size_t bytes) -> char* {
    char* r = p;
    p += (bytes + 255) & ~(size_t)255;
    return r;
  };
  float* deg = (float*)carve((size_t)N * 4);  // becomes dis in place
  int* cur = (int*)carve((size_t)N * 4);      // cursor -> in-degree count
  unsigned long long* pair =
      (unsigned long long*)carve((size_t)N * PSTR * 8);
  __half* h16 = (__half*)carve((size_t)N * 64 * 2);
  __half* t16 = (__half*)carve((size_t)N * 64 * 2);
  __half* Tx16 = (__half*)carve((size_t)4 * N * 64 * 2);
  (void)ws_size;

  hipMemsetAsync(deg, 0, (size_t)N * 4, stream);
  hipMemsetAsync(cur, 0, (size_t)N * 4, stream);
  hipMemsetAsync(pair, 0, (size_t)N * PSTR * 8, stream);  // zero pad slots

  const int gE = (E + 255) / 256;
  const int gN = (N + 255) / 256;
  k_deg<<<gE, 256, 0, stream>>>(src, ea, deg, E);
  k_dis<<<gN, 256, 0, stream>>>(deg, N);
  k_fill<<<gE, 256, 0, stream>>>(src, tgt, ea, deg, cur, pair, E);
  k_encode<<<2048, 256, 0, stream>>>(x, e1w, e1b, e2w, e2b, h16, N);

  const size_t n64 = (size_t)N * 64;
  const int gP = (N + 3) / 4;      // 4 waves/block, 1 node/wave
  const int gG = (N + 127) / 128;  // 128-row MFMA tiles
  __half* Tx1 = Tx16;
  __half* Tx2 = Tx16 + n64;
  __half* Tx3 = Tx16 + 2 * n64;
  __half* Tx4 = Tx16 + 3 * n64;
  for (int b = 0; b < 3; ++b) {
    const float* cw1b = cw1 + (size_t)b * 5 * 4096;
    const float* cb1b = cb1 + b * 64;
    const float* cw2b = cw2 + (size_t)b * 5 * 4096;
    const float* cb2b = cb2 + b * 64;
    const float* lwb = lw + (size_t)b * 4096;
    const float* lbb = lb + b * 64;

    // conv1: t16 = gelu(h@W0 + sum Tx_k@W_k + cb1)
    k_prop<false><<<gP, 256, 0, stream>>>(h16, cur, pair, nullptr, Tx1, N);
    k_prop<true><<<gP, 256, 0, stream>>>(Tx1, cur, pair, h16, Tx2, N);
    k_prop<true><<<gP, 256, 0, stream>>>(Tx2, cur, pair, Tx1, Tx3, N);
    k_prop<true><<<gP, 256, 0, stream>>>(Tx3, cur, pair, Tx2, Tx4, N);
    k_gemm_mfma<5, false, true><<<gG, 512, 0, stream>>>(
        h16, Tx16, cw1b, nullptr, nullptr, cb1b, nullptr, t16, N);

    // conv2 + residual: h16 = gelu(t@W0 + sum Ty_k@W_k + h@lw + cb2 + lb)
    k_prop<false><<<gP, 256, 0, stream>>>(t16, cur, pair, nullptr, Tx1, N);
    k_prop<true><<<gP, 256, 0, stream>>>(Tx1, cur, pair, t16, Tx2, N);
    k_prop<true><<<gP, 256, 0, stream>>>(Tx2, cur, pair, Tx1, Tx3, N);
    k_prop<true><<<gP, 256, 0, stream>>>(Tx3, cur, pair, Tx2, Tx4, N);
    k_gemm_mfma<6, true, true><<<gG, 512, 0, stream>>>(
        t16, Tx16, cw2b, h16, lwb, cb2b, lbb, h16, N);
  }

  const int gD = (int)(((size_t)N * 16 + 255) / 256);
  k_decode<<<gD, 256, 0, stream>>>(h16, d1w, d1b, d2w, d2b, (float*)d_out, N);
}

// Round 9
// 1462.492 us; speedup vs baseline: 1.0615x; 1.0615x over previous
//
#include <hip/hip_runtime.h>
#include <hip/hip_fp16.h>
#include <math.h>

// ---------------------------------------------------------------------------
// ChebConv GNN. N=100000, E=1600000, D=64, K=5, 3 residual blocks.
// Round 9:
//  - Prop: wave = 1 node; ONE predicated pair load (<=48 slots); 8 edges per
//    gather instruction (16B/lane dwordx4 = 8 x 128B rows); exact ceil(deg/8)
//    trips; 2 bpermutes per 8 edges; cross-octet xor-reduce; lanes 0-7 store.
//    Rationale: r8 showed ~6.4cyc/VMEM-op marginal cost; this cuts VMEM ops
//    per prop from ~1.55M to ~0.45M.
//  - All activations fp16; MFMA GEMMs (v_mfma_f32_16x16x32_f16) [round 6].
//  - Padded CSR (PSTR=48), one atomic per edge; no pair memset (predicated).
// ---------------------------------------------------------------------------

#define PSTR 48

typedef _Float16 f16x8 __attribute__((ext_vector_type(8)));
typedef float f32x4 __attribute__((ext_vector_type(4)));

__device__ __forceinline__ float gelu_f(float v) {
  return 0.5f * v * (1.0f + erff(v * 0.70710678118654752440f));
}

__global__ __launch_bounds__(256) void k_deg(const int* __restrict__ src,
                                             const float* __restrict__ ea,
                                             float* __restrict__ deg, int E) {
  int e = blockIdx.x * 256 + threadIdx.x;
  if (e < E) atomicAdd(&deg[src[e]], ea[e]);
}

__global__ __launch_bounds__(256) void k_dis(float* __restrict__ deg, int n) {
  int i = blockIdx.x * 256 + threadIdx.x;
  if (i < n) {
    float d = deg[i];
    deg[i] = (d > 0.f) ? rsqrtf(d) : 0.f;
  }
}

__global__ __launch_bounds__(256) void k_fill(
    const int* __restrict__ src, const int* __restrict__ tgt,
    const float* __restrict__ ea, const float* __restrict__ dis,
    int* __restrict__ cur, unsigned long long* __restrict__ pair, int E) {
  int e = blockIdx.x * 256 + threadIdx.x;
  if (e < E) {
    int s = src[e], t = tgt[e];
    int pos = atomicAdd(&cur[t], 1);
    if (pos < PSTR) {
      float w = -ea[e] * dis[s] * dis[t];
      unsigned long long v =
          (unsigned long long)(unsigned int)s |
          ((unsigned long long)__float_as_uint(w) << 32);
      pair[(size_t)t * PSTR + pos] = v;
    }
  }
}

// ---- encoder: h16 = gelu(gelu(x@w1+b1)@w2+b2) ----
__global__ __launch_bounds__(256) void k_encode(
    const float* __restrict__ x, const float* __restrict__ w1,
    const float* __restrict__ b1, const float* __restrict__ w2,
    const float* __restrict__ b2, __half* __restrict__ h16, int n) {
  __shared__ float sw1[4 * 64];
  __shared__ float sb1[64];
  __shared__ float sw2[64 * 64];
  __shared__ float sb2[64];
  __shared__ float smid[4][64];
  if (threadIdx.x < 256) sw1[threadIdx.x] = w1[threadIdx.x];
  if (threadIdx.x < 64) {
    sb1[threadIdx.x] = b1[threadIdx.x];
    sb2[threadIdx.x] = b2[threadIdx.x];
  }
  for (int i = threadIdx.x; i < 4096; i += 256) sw2[i] = w2[i];
  __syncthreads();
  const int wave = threadIdx.x >> 6;
  const int lane = threadIdx.x & 63;
  for (int base = blockIdx.x * 4; base < n; base += gridDim.x * 4) {
    const int node = base + wave;
    const bool ok = node < n;
    float m = 0.f;
    if (ok) {
      const float4 xv = *(const float4*)(x + (size_t)node * 4);
      m = xv.x * sw1[lane] + xv.y * sw1[64 + lane] + xv.z * sw1[128 + lane] +
          xv.w * sw1[192 + lane] + sb1[lane];
      m = gelu_f(m);
    }
    smid[wave][lane] = m;
    __syncthreads();
    float o = sb2[lane];
#pragma unroll 8
    for (int k = 0; k < 64; ++k) o += smid[wave][k] * sw2[k * 64 + lane];
    if (ok) h16[(size_t)node * 64 + lane] = __float2half_rn(gelu_f(o));
    __syncthreads();
  }
}

// ---- prop: out16 = [2*]segsum(fp16 gather)[- prev16]; wave = 1 node -------
// One predicated pair load (slot = lane, deg<=48). Per u-step: octet
// o=lane>>3 handles edge 8u+o; its 8 lanes read 16B each of the 128B row
// (channels (lane&7)*8..+7). acc[8] per lane; cross-octet xor-reduce; lanes
// 0-7 write the 128B output row.
template <bool HASPREV>
__global__ __launch_bounds__(256) void k_prop(
    const __half* __restrict__ hin16, const int* __restrict__ cnt,
    const unsigned long long* __restrict__ pair,
    const __half* __restrict__ prev16, __half* __restrict__ out16, int n) {
  const int node = (int)((blockIdx.x * 256 + threadIdx.x) >> 6);
  const int lane = threadIdx.x & 63;
  if (node >= n) return;
  const int deg = min(cnt[node], PSTR);

  int idx = 0;
  float w = 0.f;
  if (lane < deg) {
    const unsigned long long v =
        __builtin_nontemporal_load(pair + (size_t)node * PSTR + lane);
    idx = (int)(unsigned int)v;
    w = __uint_as_float((unsigned int)(v >> 32));
  }

  const int o = lane & 7;       // sub-lane in octet -> channels o*8..o*8+7
  const int oct = lane >> 3;    // octet = which edge of the group of 8
  const int nstep = (deg + 7) >> 3;

  float a0 = 0.f, a1 = 0.f, a2 = 0.f, a3 = 0.f;
  float a4 = 0.f, a5 = 0.f, a6 = 0.f, a7 = 0.f;
  for (int u = 0; u < nstep; ++u) {
    const int e = (u << 3) | oct;
    const int bidx = __shfl(idx, e, 64);
    const float bw = __shfl(w, e, 64);
    union { f16x8 v; __half2 h[4]; } hv;
    hv.v = *(const f16x8*)(hin16 + ((size_t)bidx << 6) + (o << 3));
    float2 f;
    f = __half22float2(hv.h[0]); a0 = fmaf(bw, f.x, a0); a1 = fmaf(bw, f.y, a1);
    f = __half22float2(hv.h[1]); a2 = fmaf(bw, f.x, a2); a3 = fmaf(bw, f.y, a3);
    f = __half22float2(hv.h[2]); a4 = fmaf(bw, f.x, a4); a5 = fmaf(bw, f.y, a5);
    f = __half22float2(hv.h[3]); a6 = fmaf(bw, f.x, a6); a7 = fmaf(bw, f.y, a7);
  }

#define RED3(x)                    \
  x += __shfl_xor(x, 8, 64);       \
  x += __shfl_xor(x, 16, 64);      \
  x += __shfl_xor(x, 32, 64);
  RED3(a0) RED3(a1) RED3(a2) RED3(a3)
  RED3(a4) RED3(a5) RED3(a6) RED3(a7)
#undef RED3

  if (lane < 8) {
    if (HASPREV) {
      union { f16x8 v; __half2 h[4]; } pv;
      pv.v = *(const f16x8*)(prev16 + ((size_t)node << 6) + (o << 3));
      float2 p;
      p = __half22float2(pv.h[0]); a0 = 2.f * a0 - p.x; a1 = 2.f * a1 - p.y;
      p = __half22float2(pv.h[1]); a2 = 2.f * a2 - p.x; a3 = 2.f * a3 - p.y;
      p = __half22float2(pv.h[2]); a4 = 2.f * a4 - p.x; a5 = 2.f * a5 - p.y;
      p = __half22float2(pv.h[3]); a6 = 2.f * a6 - p.x; a7 = 2.f * a7 - p.y;
    }
    union { f16x8 v; __half2 h[4]; } ov;
    ov.h[0] = __floats2half2_rn(a0, a1);
    ov.h[1] = __floats2half2_rn(a2, a3);
    ov.h[2] = __floats2half2_rn(a4, a5);
    ov.h[3] = __floats2half2_rn(a6, a7);
    *(f16x8*)(out16 + ((size_t)node << 6) + (o << 3)) = ov.v;
  }
}

// ---- MFMA multi-buffer GEMM -------------------------------------------------
// out16 = gelu(sum_{b<5} A_b @ W_b [+ Aex@Wex] + bias1 [+ bias2]).
// A_0=A0, A_b=Atx+(b-1)*n64. All A fp16 row-major [n][64]. W fp32 in global,
// staged fp16 in LDS pre-swizzled to b-frag order.
// 512 threads = 8 waves; wave w -> rows blk*128 + w*16 .. +15.
template <int TOT, bool HASEX, bool GELU>
__global__ __launch_bounds__(512) void k_gemm_mfma(
    const __half* __restrict__ A0, const __half* __restrict__ Atx,
    const float* __restrict__ Wb, const __half* __restrict__ Aex,
    const float* __restrict__ Wex, const float* __restrict__ bias1,
    const float* __restrict__ bias2, __half* __restrict__ out16, int n) {
  __shared__ __align__(16) _Float16 sWh[TOT * 2 * 4 * 64 * 8];
  const int tid = threadIdx.x;
  for (int b = 0; b < TOT; ++b) {
    const float* Wp = (b < 5) ? Wb + b * 4096 : Wex;
    for (int idx = tid; idx < 4096; idx += 512) {
      const int k = idx >> 6, nn = idx & 63;
      const int lane = (nn & 15) | (((k >> 3) & 3) << 4);
      const int dst =
          (((b * 2 + (k >> 5)) * 4 + (nn >> 4)) * 64 + lane) * 8 + (k & 7);
      sWh[dst] = (_Float16)Wp[idx];
    }
  }
  __syncthreads();

  const int wv = tid >> 6;
  const int lane = tid & 63;
  const int kg = lane >> 4;  // 0..3
  const int row = blockIdx.x * 128 + wv * 16 + (lane & 15);
  const bool rok = row < n;
  const size_t n64 = (size_t)n * 64;
  const f16x8* bw = (const f16x8*)sWh;

  f32x4 acc[4];
#pragma unroll
  for (int ct = 0; ct < 4; ++ct) acc[ct] = (f32x4){0.f, 0.f, 0.f, 0.f};

  for (int b = 0; b < TOT; ++b) {
    const __half* Ap =
        (b == 0) ? A0 : (b < 5 ? Atx + (size_t)(b - 1) * n64 : Aex);
    f16x8 a0 = {}, a1 = {};
    if (rok) {
      a0 = *(const f16x8*)(Ap + (size_t)row * 64 + kg * 8);
      a1 = *(const f16x8*)(Ap + (size_t)row * 64 + 32 + kg * 8);
    }
#pragma unroll
    for (int ct = 0; ct < 4; ++ct) {
      const f16x8 b0 = bw[((b * 2 + 0) * 4 + ct) * 64 + lane];
      const f16x8 b1 = bw[((b * 2 + 1) * 4 + ct) * 64 + lane];
      acc[ct] = __builtin_amdgcn_mfma_f32_16x16x32_f16(a0, b0, acc[ct], 0, 0, 0);
      acc[ct] = __builtin_amdgcn_mfma_f32_16x16x32_f16(a1, b1, acc[ct], 0, 0, 0);
    }
  }

  const int orow0 = blockIdx.x * 128 + wv * 16 + (lane >> 4) * 4;
#pragma unroll
  for (int ct = 0; ct < 4; ++ct) {
    const int col = ct * 16 + (lane & 15);
    float bb = bias1[col];
    if (HASEX) bb += bias2[col];
#pragma unroll
    for (int j = 0; j < 4; ++j) {
      const int r = orow0 + j;
      if (r < n) {
        float v = acc[ct][j] + bb;
        if (GELU) v = gelu_f(v);
        out16[(size_t)r * 64 + col] = __float2half_rn(v);
      }
    }
  }
}

// ---- decoder: out[n] = gelu(dot(h16[n], d1w) + d1b)*d2w + d2b ----
__global__ __launch_bounds__(256) void k_decode(
    const __half* __restrict__ h16, const float* __restrict__ d1w,
    const float* __restrict__ d1b, const float* __restrict__ d2w,
    const float* __restrict__ d2b, float* __restrict__ out, int n) {
  const int q = (blockIdx.x * 256 + threadIdx.x) >> 4;  // node
  const int l = threadIdx.x & 15;
  if (q >= n) return;
  union { short4 s; __half2 h[2]; } u;
  u.s = *(const short4*)(h16 + (size_t)q * 64 + l * 4);
  const float2 v01 = __half22float2(u.h[0]);
  const float2 v23 = __half22float2(u.h[1]);
  const float4 w = *(const float4*)(d1w + l * 4);
  float s = v01.x * w.x + v01.y * w.y + v23.x * w.z + v23.y * w.w;
  s += __shfl_xor(s, 1, 64);
  s += __shfl_xor(s, 2, 64);
  s += __shfl_xor(s, 4, 64);
  s += __shfl_xor(s, 8, 64);
  if (l == 0) out[q] = gelu_f(s + d1b[0]) * d2w[0] + d2b[0];
}

extern "C" void kernel_launch(void* const* d_in, const int* in_sizes, int n_in,
                              void* d_out, int out_size, void* d_ws,
                              size_t ws_size, hipStream_t stream) {
  const float* x = (const float*)d_in[0];
  const int* ei = (const int*)d_in[1];
  const float* ea = (const float*)d_in[2];
  const float* e1w = (const float*)d_in[3];
  const float* e1b = (const float*)d_in[4];
  const float* e2w = (const float*)d_in[5];
  const float* e2b = (const float*)d_in[6];
  const float* cw1 = (const float*)d_in[7];
  const float* cb1 = (const float*)d_in[8];
  const float* cw2 = (const float*)d_in[9];
  const float* cb2 = (const float*)d_in[10];
  const float* lw = (const float*)d_in[11];
  const float* lb = (const float*)d_in[12];
  const float* d1w = (const float*)d_in[13];
  const float* d1b = (const float*)d_in[14];
  const float* d2w = (const float*)d_in[15];
  const float* d2b = (const float*)d_in[16];

  const int N = in_sizes[0] / 4;
  const int E = in_sizes[2];
  const int* src = ei;
  const int* tgt = ei + E;

  char* p = (char*)d_ws;
  auto carve = [&](size_t bytes) -> char* {
    char* r = p;
    p += (bytes + 255) & ~(size_t)255;
    return r;
  };
  float* deg = (float*)carve((size_t)N * 4);  // becomes dis in place
  int* cur = (int*)carve((size_t)N * 4);      // cursor -> in-degree count
  unsigned long long* pair =
      (unsigned long long*)carve((size_t)N * PSTR * 8);
  __half* h16 = (__half*)carve((size_t)N * 64 * 2);
  __half* t16 = (__half*)carve((size_t)N * 64 * 2);
  __half* Tx16 = (__half*)carve((size_t)4 * N * 64 * 2);
  (void)ws_size;

  hipMemsetAsync(deg, 0, (size_t)N * 4, stream);
  hipMemsetAsync(cur, 0, (size_t)N * 4, stream);

  const int gE = (E + 255) / 256;
  const int gN = (N + 255) / 256;
  k_deg<<<gE, 256, 0, stream>>>(src, ea, deg, E);
  k_dis<<<gN, 256, 0, stream>>>(deg, N);
  k_fill<<<gE, 256, 0, stream>>>(src, tgt, ea, deg, cur, pair, E);
  k_encode<<<2048, 256, 0, stream>>>(x, e1w, e1b, e2w, e2b, h16, N);

  const size_t n64 = (size_t)N * 64;
  const int gP = (N + 3) / 4;      // 4 waves/block, 1 node/wave
  const int gG = (N + 127) / 128;  // 128-row MFMA tiles
  __half* Tx1 = Tx16;
  __half* Tx2 = Tx16 + n64;
  __half* Tx3 = Tx16 + 2 * n64;
  __half* Tx4 = Tx16 + 3 * n64;
  for (int b = 0; b < 3; ++b) {
    const float* cw1b = cw1 + (size_t)b * 5 * 4096;
    const float* cb1b = cb1 + b * 64;
    const float* cw2b = cw2 + (size_t)b * 5 * 4096;
    const float* cb2b = cb2 + b * 64;
    const float* lwb = lw + (size_t)b * 4096;
    const float* lbb = lb + b * 64;

    // conv1: t16 = gelu(h@W0 + sum Tx_k@W_k + cb1)
    k_prop<false><<<gP, 256, 0, stream>>>(h16, cur, pair, nullptr, Tx1, N);
    k_prop<true><<<gP, 256, 0, stream>>>(Tx1, cur, pair, h16, Tx2, N);
    k_prop<true><<<gP, 256, 0, stream>>>(Tx2, cur, pair, Tx1, Tx3, N);
    k_prop<true><<<gP, 256, 0, stream>>>(Tx3, cur, pair, Tx2, Tx4, N);
    k_gemm_mfma<5, false, true><<<gG, 512, 0, stream>>>(
        h16, Tx16, cw1b, nullptr, nullptr, cb1b, nullptr, t16, N);

    // conv2 + residual: h16 = gelu(t@W0 + sum Ty_k@W_k + h@lw + cb2 + lb)
    k_prop<false><<<gP, 256, 0, stream>>>(t16, cur, pair, nullptr, Tx1, N);
    k_prop<true><<<gP, 256, 0, stream>>>(Tx1, cur, pair, t16, Tx2, N);
    k_prop<true><<<gP, 256, 0, stream>>>(Tx2, cur, pair, Tx1, Tx3, N);
    k_prop<true><<<gP, 256, 0, stream>>>(Tx3, cur, pair, Tx2, Tx4, N);
    k_gemm_mfma<6, true, true><<<gG, 512, 0, stream>>>(
        t16, Tx16, cw2b, h16, lwb, cb2b, lbb, h16, N);
  }

  const int gD = (int)(((size_t)N * 16 + 255) / 256);
  k_decode<<<gD, 256, 0, stream>>>(h16, d1w, d1b, d2w, d2b, (float*)d_out, N);
}

// Round 10
// 1423.343 us; speedup vs baseline: 1.0907x; 1.0275x over previous
//
#include <hip/hip_runtime.h>
#include <hip/hip_fp16.h>
#include <math.h>

// ---------------------------------------------------------------------------
// ChebConv GNN. N=100000, E=1600000, D=64, K=5, 3 residual blocks.
// Round 10 (= round 6 base + scalar-pair dual-edge prop):
//  - Prop: wave = 1 node. node forced uniform via readfirstlane -> (idx,w)
//    pair loads become s_load (scalar pipe, SGPR broadcast, no bpermute).
//    Each gather instr covers 2 edges (half-wave per row, 4B/lane, 256B).
//    Exact ceil(deg/2) trips; pair buffer zero-padded (memset) so no tail.
//  - All activations fp16; MFMA GEMMs (v_mfma_f32_16x16x32_f16).
//  - Padded CSR (PSTR=48), one atomic per edge.
// ---------------------------------------------------------------------------

#define PSTR 48

typedef _Float16 f16x8 __attribute__((ext_vector_type(8)));
typedef float f32x4 __attribute__((ext_vector_type(4)));

__device__ __forceinline__ float gelu_f(float v) {
  return 0.5f * v * (1.0f + erff(v * 0.70710678118654752440f));
}

__global__ __launch_bounds__(256) void k_deg(const int* __restrict__ src,
                                             const float* __restrict__ ea,
                                             float* __restrict__ deg, int E) {
  int e = blockIdx.x * 256 + threadIdx.x;
  if (e < E) atomicAdd(&deg[src[e]], ea[e]);
}

__global__ __launch_bounds__(256) void k_dis(float* __restrict__ deg, int n) {
  int i = blockIdx.x * 256 + threadIdx.x;
  if (i < n) {
    float d = deg[i];
    deg[i] = (d > 0.f) ? rsqrtf(d) : 0.f;
  }
}

__global__ __launch_bounds__(256) void k_fill(
    const int* __restrict__ src, const int* __restrict__ tgt,
    const float* __restrict__ ea, const float* __restrict__ dis,
    int* __restrict__ cur, unsigned long long* __restrict__ pair, int E) {
  int e = blockIdx.x * 256 + threadIdx.x;
  if (e < E) {
    int s = src[e], t = tgt[e];
    int pos = atomicAdd(&cur[t], 1);
    if (pos < PSTR) {
      float w = -ea[e] * dis[s] * dis[t];
      unsigned long long v =
          (unsigned long long)(unsigned int)s |
          ((unsigned long long)__float_as_uint(w) << 32);
      pair[(size_t)t * PSTR + pos] = v;
    }
  }
}

// ---- encoder: h16 = gelu(gelu(x@w1+b1)@w2+b2) ----
__global__ __launch_bounds__(256) void k_encode(
    const float* __restrict__ x, const float* __restrict__ w1,
    const float* __restrict__ b1, const float* __restrict__ w2,
    const float* __restrict__ b2, __half* __restrict__ h16, int n) {
  __shared__ float sw1[4 * 64];
  __shared__ float sb1[64];
  __shared__ float sw2[64 * 64];
  __shared__ float sb2[64];
  __shared__ float smid[4][64];
  if (threadIdx.x < 256) sw1[threadIdx.x] = w1[threadIdx.x];
  if (threadIdx.x < 64) {
    sb1[threadIdx.x] = b1[threadIdx.x];
    sb2[threadIdx.x] = b2[threadIdx.x];
  }
  for (int i = threadIdx.x; i < 4096; i += 256) sw2[i] = w2[i];
  __syncthreads();
  const int wave = threadIdx.x >> 6;
  const int lane = threadIdx.x & 63;
  for (int base = blockIdx.x * 4; base < n; base += gridDim.x * 4) {
    const int node = base + wave;
    const bool ok = node < n;
    float m = 0.f;
    if (ok) {
      const float4 xv = *(const float4*)(x + (size_t)node * 4);
      m = xv.x * sw1[lane] + xv.y * sw1[64 + lane] + xv.z * sw1[128 + lane] +
          xv.w * sw1[192 + lane] + sb1[lane];
      m = gelu_f(m);
    }
    smid[wave][lane] = m;
    __syncthreads();
    float o = sb2[lane];
#pragma unroll 8
    for (int k = 0; k < 64; ++k) o += smid[wave][k] * sw2[k * 64 + lane];
    if (ok) h16[(size_t)node * 64 + lane] = __float2half_rn(gelu_f(o));
    __syncthreads();
  }
}

// ---- prop: out16 = [2*]segsum(fp16 gather)[- prev16]; wave = 1 node -------
// node/deg forced wave-uniform (readfirstlane) -> pair loads scalarize to
// s_load (SGPR broadcast). Each gather: lanes 0-31 read edge j's 128B row,
// lanes 32-63 read edge j+1's row (4B half2 per lane). Exact ceil(deg/2)
// trips; zero-padded pair slots contribute w=0. Final half-combine via one
// shfl_xor(32); lanes 0-31 handle prev/out (128B row).
template <bool HASPREV>
__global__ __launch_bounds__(256) void k_prop(
    const __half* __restrict__ hin16, const int* __restrict__ cnt,
    const unsigned long long* __restrict__ pair,
    const __half* __restrict__ prev16, __half* __restrict__ out16, int n) {
  int node = (int)(blockIdx.x * 4 + (threadIdx.x >> 6));
  node = __builtin_amdgcn_readfirstlane(node);
  if (node >= n) return;
  const int lane = threadIdx.x & 63;
  const int hl = lane & 31;   // channel pair: channels 2*hl, 2*hl+1
  const int sel = lane >> 5;  // which edge of the duo this half serves
  const int deg = __builtin_amdgcn_readfirstlane(min(cnt[node], PSTR));
  const unsigned long long* __restrict__ prow = pair + (size_t)node * PSTR;

  float ax = 0.f, ay = 0.f;
  const int dceil = (deg + 1) & ~1;
#pragma unroll 4
  for (int j = 0; j < dceil; j += 2) {
    const unsigned long long p0 = prow[j];      // scalar (uniform) loads
    const unsigned long long p1 = prow[j + 1];  // pad slot -> 0 (w=0)
    const int i0 = (int)(unsigned int)p0;
    const int i1 = (int)(unsigned int)p1;
    const float w0 = __uint_as_float((unsigned int)(p0 >> 32));
    const float w1 = __uint_as_float((unsigned int)(p1 >> 32));
    const int bidx = sel ? i1 : i0;
    const float bw = sel ? w1 : w0;
    const __half2 hv =
        *(const __half2*)(hin16 + ((size_t)bidx << 6) + (hl << 1));
    const float2 f = __half22float2(hv);
    ax = fmaf(bw, f.x, ax);
    ay = fmaf(bw, f.y, ay);
  }
  // combine the two halves' partial sums
  ax += __shfl_xor(ax, 32, 64);
  ay += __shfl_xor(ay, 32, 64);
  if (lane < 32) {
    float rx = ax, ry = ay;
    if (HASPREV) {
      const float2 pf = __half22float2(
          *(const __half2*)(prev16 + ((size_t)node << 6) + (hl << 1)));
      rx = 2.f * ax - pf.x;
      ry = 2.f * ay - pf.y;
    }
    *(__half2*)(out16 + ((size_t)node << 6) + (hl << 1)) =
        __floats2half2_rn(rx, ry);
  }
}

// ---- MFMA multi-buffer GEMM -------------------------------------------------
// out16 = gelu(sum_{b<5} A_b @ W_b [+ Aex@Wex] + bias1 [+ bias2]).
// A_0=A0, A_b=Atx+(b-1)*n64. All A fp16 row-major [n][64]. W fp32 in global,
// staged fp16 in LDS pre-swizzled to b-frag order.
// 512 threads = 8 waves; wave w -> rows blk*128 + w*16 .. +15.
template <int TOT, bool HASEX, bool GELU>
__global__ __launch_bounds__(512) void k_gemm_mfma(
    const __half* __restrict__ A0, const __half* __restrict__ Atx,
    const float* __restrict__ Wb, const __half* __restrict__ Aex,
    const float* __restrict__ Wex, const float* __restrict__ bias1,
    const float* __restrict__ bias2, __half* __restrict__ out16, int n) {
  __shared__ __align__(16) _Float16 sWh[TOT * 2 * 4 * 64 * 8];
  const int tid = threadIdx.x;
  for (int b = 0; b < TOT; ++b) {
    const float* Wp = (b < 5) ? Wb + b * 4096 : Wex;
    for (int idx = tid; idx < 4096; idx += 512) {
      const int k = idx >> 6, nn = idx & 63;
      const int lane = (nn & 15) | (((k >> 3) & 3) << 4);
      const int dst =
          (((b * 2 + (k >> 5)) * 4 + (nn >> 4)) * 64 + lane) * 8 + (k & 7);
      sWh[dst] = (_Float16)Wp[idx];
    }
  }
  __syncthreads();

  const int wv = tid >> 6;
  const int lane = tid & 63;
  const int kg = lane >> 4;  // 0..3
  const int row = blockIdx.x * 128 + wv * 16 + (lane & 15);
  const bool rok = row < n;
  const size_t n64 = (size_t)n * 64;
  const f16x8* bw = (const f16x8*)sWh;

  f32x4 acc[4];
#pragma unroll
  for (int ct = 0; ct < 4; ++ct) acc[ct] = (f32x4){0.f, 0.f, 0.f, 0.f};

  for (int b = 0; b < TOT; ++b) {
    const __half* Ap =
        (b == 0) ? A0 : (b < 5 ? Atx + (size_t)(b - 1) * n64 : Aex);
    f16x8 a0 = {}, a1 = {};
    if (rok) {
      a0 = *(const f16x8*)(Ap + (size_t)row * 64 + kg * 8);
      a1 = *(const f16x8*)(Ap + (size_t)row * 64 + 32 + kg * 8);
    }
#pragma unroll
    for (int ct = 0; ct < 4; ++ct) {
      const f16x8 b0 = bw[((b * 2 + 0) * 4 + ct) * 64 + lane];
      const f16x8 b1 = bw[((b * 2 + 1) * 4 + ct) * 64 + lane];
      acc[ct] = __builtin_amdgcn_mfma_f32_16x16x32_f16(a0, b0, acc[ct], 0, 0, 0);
      acc[ct] = __builtin_amdgcn_mfma_f32_16x16x32_f16(a1, b1, acc[ct], 0, 0, 0);
    }
  }

  const int orow0 = blockIdx.x * 128 + wv * 16 + (lane >> 4) * 4;
#pragma unroll
  for (int ct = 0; ct < 4; ++ct) {
    const int col = ct * 16 + (lane & 15);
    float bb = bias1[col];
    if (HASEX) bb += bias2[col];
#pragma unroll
    for (int j = 0; j < 4; ++j) {
      const int r = orow0 + j;
      if (r < n) {
        float v = acc[ct][j] + bb;
        if (GELU) v = gelu_f(v);
        out16[(size_t)r * 64 + col] = __float2half_rn(v);
      }
    }
  }
}

// ---- decoder: out[n] = gelu(dot(h16[n], d1w) + d1b)*d2w + d2b ----
__global__ __launch_bounds__(256) void k_decode(
    const __half* __restrict__ h16, const float* __restrict__ d1w,
    const float* __restrict__ d1b, const float* __restrict__ d2w,
    const float* __restrict__ d2b, float* __restrict__ out, int n) {
  const int q = (blockIdx.x * 256 + threadIdx.x) >> 4;  // node
  const int l = threadIdx.x & 15;
  if (q >= n) return;
  union { short4 s; __half2 h[2]; } u;
  u.s = *(const short4*)(h16 + (size_t)q * 64 + l * 4);
  const float2 v01 = __half22float2(u.h[0]);
  const float2 v23 = __half22float2(u.h[1]);
  const float4 w = *(const float4*)(d1w + l * 4);
  float s = v01.x * w.x + v01.y * w.y + v23.x * w.z + v23.y * w.w;
  s += __shfl_xor(s, 1, 64);
  s += __shfl_xor(s, 2, 64);
  s += __shfl_xor(s, 4, 64);
  s += __shfl_xor(s, 8, 64);
  if (l == 0) out[q] = gelu_f(s + d1b[0]) * d2w[0] + d2b[0];
}

extern "C" void kernel_launch(void* const* d_in, const int* in_sizes, int n_in,
                              void* d_out, int out_size, void* d_ws,
                              size_t ws_size, hipStream_t stream) {
  const float* x = (const float*)d_in[0];
  const int* ei = (const int*)d_in[1];
  const float* ea = (const float*)d_in[2];
  const float* e1w = (const float*)d_in[3];
  const float* e1b = (const float*)d_in[4];
  const float* e2w = (const float*)d_in[5];
  const float* e2b = (const float*)d_in[6];
  const float* cw1 = (const float*)d_in[7];
  const float* cb1 = (const float*)d_in[8];
  const float* cw2 = (const float*)d_in[9];
  const float* cb2 = (const float*)d_in[10];
  const float* lw = (const float*)d_in[11];
  const float* lb = (const float*)d_in[12];
  const float* d1w = (const float*)d_in[13];
  const float* d1b = (const float*)d_in[14];
  const float* d2w = (const float*)d_in[15];
  const float* d2b = (const float*)d_in[16];

  const int N = in_sizes[0] / 4;
  const int E = in_sizes[2];
  const int* src = ei;
  const int* tgt = ei + E;

  char* p = (char*)d_ws;
  auto carve = [&](size_t bytes) -> char* {
    char* r = p;
    p += (bytes + 255) & ~(size_t)255;
    return r;
  };
  float* deg = (float*)carve((size_t)N * 4);  // becomes dis in place
  int* cur = (int*)carve((size_t)N * 4);      // cursor -> in-degree count
  unsigned long long* pair =
      (unsigned long long*)carve((size_t)N * PSTR * 8);
  __half* h16 = (__half*)carve((size_t)N * 64 * 2);
  __half* t16 = (__half*)carve((size_t)N * 64 * 2);
  __half* Tx16 = (__half*)carve((size_t)4 * N * 64 * 2);
  (void)ws_size;

  hipMemsetAsync(deg, 0, (size_t)N * 4, stream);
  hipMemsetAsync(cur, 0, (size_t)N * 4, stream);
  hipMemsetAsync(pair, 0, (size_t)N * PSTR * 8, stream);  // zero pad slots

  const int gE = (E + 255) / 256;
  const int gN = (N + 255) / 256;
  k_deg<<<gE, 256, 0, stream>>>(src, ea, deg, E);
  k_dis<<<gN, 256, 0, stream>>>(deg, N);
  k_fill<<<gE, 256, 0, stream>>>(src, tgt, ea, deg, cur, pair, E);
  k_encode<<<2048, 256, 0, stream>>>(x, e1w, e1b, e2w, e2b, h16, N);

  const size_t n64 = (size_t)N * 64;
  const int gP = (N + 3) / 4;      // 4 waves/block, 1 node/wave
  const int gG = (N + 127) / 128;  // 128-row MFMA tiles
  __half* Tx1 = Tx16;
  __half* Tx2 = Tx16 + n64;
  __half* Tx3 = Tx16 + 2 * n64;
  __half* Tx4 = Tx16 + 3 * n64;
  for (int b = 0; b < 3; ++b) {
    const float* cw1b = cw1 + (size_t)b * 5 * 4096;
    const float* cb1b = cb1 + b * 64;
    const float* cw2b = cw2 + (size_t)b * 5 * 4096;
    const float* cb2b = cb2 + b * 64;
    const float* lwb = lw + (size_t)b * 4096;
    const float* lbb = lb + b * 64;

    // conv1: t16 = gelu(h@W0 + sum Tx_k@W_k + cb1)
    k_prop<false><<<gP, 256, 0, stream>>>(h16, cur, pair, nullptr, Tx1, N);
    k_prop<true><<<gP, 256, 0, stream>>>(Tx1, cur, pair, h16, Tx2, N);
    k_prop<true><<<gP, 256, 0, stream>>>(Tx2, cur, pair, Tx1, Tx3, N);
    k_prop<true><<<gP, 256, 0, stream>>>(Tx3, cur, pair, Tx2, Tx4, N);
    k_gemm_mfma<5, false, true><<<gG, 512, 0, stream>>>(
        h16, Tx16, cw1b, nullptr, nullptr, cb1b, nullptr, t16, N);

    // conv2 + residual: h16 = gelu(t@W0 + sum Ty_k@W_k + h@lw + cb2 + lb)
    k_prop<false><<<gP, 256, 0, stream>>>(t16, cur, pair, nullptr, Tx1, N);
    k_prop<true><<<gP, 256, 0, stream>>>(Tx1, cur, pair, t16, Tx2, N);
    k_prop<true><<<gP, 256, 0, stream>>>(Tx2, cur, pair, Tx1, Tx3, N);
    k_prop<true><<<gP, 256, 0, stream>>>(Tx3, cur, pair, Tx2, Tx4, N);
    k_gemm_mfma<6, true, true><<<gG, 512, 0, stream>>>(
        t16, Tx16, cw2b, h16, lwb, cb2b, lbb, h16, N);
  }

  const int gD = (int)(((size_t)N * 16 + 255) / 256);
  k_decode<<<gD, 256, 0, stream>>>(h16, d1w, d1b, d2w, d2b, (float*)d_out, N);
}

// Round 11
// 1211.687 us; speedup vs baseline: 1.2813x; 1.1747x over previous
//
#include <hip/hip_runtime.h>
#include <hip/hip_fp16.h>
#include <math.h>

// ---------------------------------------------------------------------------
// ChebConv GNN. N=100000, E=1600000, D=64, K=5, 3 residual blocks.
// Round 11 (= round 6 base + fused CSR build):
//  - k_deg_fill: ONE edge pass does deg atomicAdd AND cursor scatter of
//    (src, raw ea). k_scale then rewrites w = -ea*dis[src]*dis[tgt].
//  - Prop: round-6 dual-node (2 nodes/wave, half2/lane, 16-edge batches,
//    per-half __shfl broadcast) — best measured (38.6us/prop).
//  - All activations fp16; MFMA GEMMs (v_mfma_f32_16x16x32_f16).
//  - Padded CSR (PSTR=48), one atomic per edge.
// ---------------------------------------------------------------------------

#define PSTR 48

typedef _Float16 f16x8 __attribute__((ext_vector_type(8)));
typedef float f32x4 __attribute__((ext_vector_type(4)));

__device__ __forceinline__ float gelu_f(float v) {
  return 0.5f * v * (1.0f + erff(v * 0.70710678118654752440f));
}

// fused: deg[src] += ea  AND  pair[tgt*PSTR + cur[tgt]++] = (src, ea_raw)
__global__ __launch_bounds__(256) void k_deg_fill(
    const int* __restrict__ src, const int* __restrict__ tgt,
    const float* __restrict__ ea, float* __restrict__ deg,
    int* __restrict__ cur, unsigned long long* __restrict__ pair, int E) {
  int e = blockIdx.x * 256 + threadIdx.x;
  if (e < E) {
    const int s = src[e];
    const int t = tgt[e];
    const float a = ea[e];
    atomicAdd(&deg[s], a);
    int pos = atomicAdd(&cur[t], 1);
    if (pos < PSTR) {
      unsigned long long v =
          (unsigned long long)(unsigned int)s |
          ((unsigned long long)__float_as_uint(a) << 32);
      pair[(size_t)t * PSTR + pos] = v;
    }
  }
}

__global__ __launch_bounds__(256) void k_dis(float* __restrict__ deg, int n) {
  int i = blockIdx.x * 256 + threadIdx.x;
  if (i < n) {
    float d = deg[i];
    deg[i] = (d > 0.f) ? rsqrtf(d) : 0.f;
  }
}

// rewrite pair weights: w = -ea * dis[src] * dis[tgt]. wave per node.
__global__ __launch_bounds__(256) void k_scale(
    const float* __restrict__ dis, const int* __restrict__ cnt,
    unsigned long long* __restrict__ pair, int n) {
  const int node = (int)((blockIdx.x * 256 + threadIdx.x) >> 6);
  const int lane = threadIdx.x & 63;
  if (node >= n) return;
  const int deg = min(cnt[node], PSTR);
  if (lane < deg) {
    const size_t p = (size_t)node * PSTR + lane;
    const unsigned long long v = pair[p];
    const int s = (int)(unsigned int)v;
    const float a = __uint_as_float((unsigned int)(v >> 32));
    const float w = -a * dis[s] * dis[node];
    pair[p] = (unsigned long long)(unsigned int)s |
              ((unsigned long long)__float_as_uint(w) << 32);
  }
}

// ---- encoder: h16 = gelu(gelu(x@w1+b1)@w2+b2) ----
__global__ __launch_bounds__(256) void k_encode(
    const float* __restrict__ x, const float* __restrict__ w1,
    const float* __restrict__ b1, const float* __restrict__ w2,
    const float* __restrict__ b2, __half* __restrict__ h16, int n) {
  __shared__ float sw1[4 * 64];
  __shared__ float sb1[64];
  __shared__ float sw2[64 * 64];
  __shared__ float sb2[64];
  __shared__ float smid[4][64];
  if (threadIdx.x < 256) sw1[threadIdx.x] = w1[threadIdx.x];
  if (threadIdx.x < 64) {
    sb1[threadIdx.x] = b1[threadIdx.x];
    sb2[threadIdx.x] = b2[threadIdx.x];
  }
  for (int i = threadIdx.x; i < 4096; i += 256) sw2[i] = w2[i];
  __syncthreads();
  const int wave = threadIdx.x >> 6;
  const int lane = threadIdx.x & 63;
  for (int base = blockIdx.x * 4; base < n; base += gridDim.x * 4) {
    const int node = base + wave;
    const bool ok = node < n;
    float m = 0.f;
    if (ok) {
      const float4 xv = *(const float4*)(x + (size_t)node * 4);
      m = xv.x * sw1[lane] + xv.y * sw1[64 + lane] + xv.z * sw1[128 + lane] +
          xv.w * sw1[192 + lane] + sb1[lane];
      m = gelu_f(m);
    }
    smid[wave][lane] = m;
    __syncthreads();
    float o = sb2[lane];
#pragma unroll 8
    for (int k = 0; k < 64; ++k) o += smid[wave][k] * sw2[k * 64 + lane];
    if (ok) h16[(size_t)node * 64 + lane] = __float2half_rn(gelu_f(o));
    __syncthreads();
  }
}

// ---- prop (round-6): out16 = [2*]segsum(fp16 gather)[- prev16] ------------
// Wave = 2 nodes: lanes 0-31 node (2*wid), lanes 32-63 node (2*wid+1).
// Lane handles channel pair (hl*2, hl*2+1) as half2. Batches of 16 edges per
// half; lanes hl<16 load (idx,w) pairs; per-half __shfl broadcast; one gather
// instruction fetches both halves' 128B rows (256B).
template <bool HASPREV>
__global__ __launch_bounds__(256) void k_prop(
    const __half* __restrict__ hin16, const int* __restrict__ cnt,
    const unsigned long long* __restrict__ pair,
    const __half* __restrict__ prev16, __half* __restrict__ out16, int n) {
  const int wid = (int)((blockIdx.x * 256 + threadIdx.x) >> 6);
  const int lane = threadIdx.x & 63;
  const int hl = lane & 31;
  const int node = (wid << 1) + (lane >> 5);
  if ((wid << 1) >= n) return;
  const bool ok = node < n;
  const int deg = ok ? min(cnt[node], PSTR) : 0;
  const size_t pbase = (size_t)node * PSTR;
  const int sbase = lane & 32;
  float accx = 0.f, accy = 0.f;
  for (int j0 = 0; __any(j0 < deg); j0 += 16) {
    int idx = 0;
    float w = 0.f;
    const int slot = j0 + (hl & 15);
    if (slot < deg) {
      const unsigned long long v =
          __builtin_nontemporal_load(pair + pbase + slot);
      idx = (int)(unsigned int)v;
      w = __uint_as_float((unsigned int)(v >> 32));
    }
#pragma unroll
    for (int u = 0; u < 16; ++u) {
      const int bidx = __shfl(idx, sbase + u, 64);
      const float bw = __shfl(w, sbase + u, 64);
      const __half2 hv =
          *(const __half2*)(hin16 + ((size_t)bidx << 6) + (hl << 1));
      const float2 f = __half22float2(hv);
      accx = fmaf(bw, f.x, accx);
      accy = fmaf(bw, f.y, accy);
    }
  }
  if (ok) {
    float rx = accx, ry = accy;
    if (HASPREV) {
      const float2 pf = __half22float2(
          *(const __half2*)(prev16 + ((size_t)node << 6) + (hl << 1)));
      rx = 2.f * accx - pf.x;
      ry = 2.f * accy - pf.y;
    }
    *(__half2*)(out16 + ((size_t)node << 6) + (hl << 1)) =
        __floats2half2_rn(rx, ry);
  }
}

// ---- MFMA multi-buffer GEMM -------------------------------------------------
// out16 = gelu(sum_{b<5} A_b @ W_b [+ Aex@Wex] + bias1 [+ bias2]).
// A_0=A0, A_b=Atx+(b-1)*n64. All A fp16 row-major [n][64]. W fp32 in global,
// staged fp16 in LDS pre-swizzled to b-frag order.
// 512 threads = 8 waves; wave w -> rows blk*128 + w*16 .. +15.
template <int TOT, bool HASEX, bool GELU>
__global__ __launch_bounds__(512) void k_gemm_mfma(
    const __half* __restrict__ A0, const __half* __restrict__ Atx,
    const float* __restrict__ Wb, const __half* __restrict__ Aex,
    const float* __restrict__ Wex, const float* __restrict__ bias1,
    const float* __restrict__ bias2, __half* __restrict__ out16, int n) {
  __shared__ __align__(16) _Float16 sWh[TOT * 2 * 4 * 64 * 8];
  const int tid = threadIdx.x;
  for (int b = 0; b < TOT; ++b) {
    const float* Wp = (b < 5) ? Wb + b * 4096 : Wex;
    for (int idx = tid; idx < 4096; idx += 512) {
      const int k = idx >> 6, nn = idx & 63;
      const int lane = (nn & 15) | (((k >> 3) & 3) << 4);
      const int dst =
          (((b * 2 + (k >> 5)) * 4 + (nn >> 4)) * 64 + lane) * 8 + (k & 7);
      sWh[dst] = (_Float16)Wp[idx];
    }
  }
  __syncthreads();

  const int wv = tid >> 6;
  const int lane = tid & 63;
  const int kg = lane >> 4;  // 0..3
  const int row = blockIdx.x * 128 + wv * 16 + (lane & 15);
  const bool rok = row < n;
  const size_t n64 = (size_t)n * 64;
  const f16x8* bw = (const f16x8*)sWh;

  f32x4 acc[4];
#pragma unroll
  for (int ct = 0; ct < 4; ++ct) acc[ct] = (f32x4){0.f, 0.f, 0.f, 0.f};

  for (int b = 0; b < TOT; ++b) {
    const __half* Ap =
        (b == 0) ? A0 : (b < 5 ? Atx + (size_t)(b - 1) * n64 : Aex);
    f16x8 a0 = {}, a1 = {};
    if (rok) {
      a0 = *(const f16x8*)(Ap + (size_t)row * 64 + kg * 8);
      a1 = *(const f16x8*)(Ap + (size_t)row * 64 + 32 + kg * 8);
    }
#pragma unroll
    for (int ct = 0; ct < 4; ++ct) {
      const f16x8 b0 = bw[((b * 2 + 0) * 4 + ct) * 64 + lane];
      const f16x8 b1 = bw[((b * 2 + 1) * 4 + ct) * 64 + lane];
      acc[ct] = __builtin_amdgcn_mfma_f32_16x16x32_f16(a0, b0, acc[ct], 0, 0, 0);
      acc[ct] = __builtin_amdgcn_mfma_f32_16x16x32_f16(a1, b1, acc[ct], 0, 0, 0);
    }
  }

  const int orow0 = blockIdx.x * 128 + wv * 16 + (lane >> 4) * 4;
#pragma unroll
  for (int ct = 0; ct < 4; ++ct) {
    const int col = ct * 16 + (lane & 15);
    float bb = bias1[col];
    if (HASEX) bb += bias2[col];
#pragma unroll
    for (int j = 0; j < 4; ++j) {
      const int r = orow0 + j;
      if (r < n) {
        float v = acc[ct][j] + bb;
        if (GELU) v = gelu_f(v);
        out16[(size_t)r * 64 + col] = __float2half_rn(v);
      }
    }
  }
}

// ---- decoder: out[n] = gelu(dot(h16[n], d1w) + d1b)*d2w + d2b ----
__global__ __launch_bounds__(256) void k_decode(
    const __half* __restrict__ h16, const float* __restrict__ d1w,
    const float* __restrict__ d1b, const float* __restrict__ d2w,
    const float* __restrict__ d2b, float* __restrict__ out, int n) {
  const int q = (blockIdx.x * 256 + threadIdx.x) >> 4;  // node
  const int l = threadIdx.x & 15;
  if (q >= n) return;
  union { short4 s; __half2 h[2]; } u;
  u.s = *(const short4*)(h16 + (size_t)q * 64 + l * 4);
  const float2 v01 = __half22float2(u.h[0]);
  const float2 v23 = __half22float2(u.h[1]);
  const float4 w = *(const float4*)(d1w + l * 4);
  float s = v01.x * w.x + v01.y * w.y + v23.x * w.z + v23.y * w.w;
  s += __shfl_xor(s, 1, 64);
  s += __shfl_xor(s, 2, 64);
  s += __shfl_xor(s, 4, 64);
  s += __shfl_xor(s, 8, 64);
  if (l == 0) out[q] = gelu_f(s + d1b[0]) * d2w[0] + d2b[0];
}

extern "C" void kernel_launch(void* const* d_in, const int* in_sizes, int n_in,
                              void* d_out, int out_size, void* d_ws,
                              size_t ws_size, hipStream_t stream) {
  const float* x = (const float*)d_in[0];
  const int* ei = (const int*)d_in[1];
  const float* ea = (const float*)d_in[2];
  const float* e1w = (const float*)d_in[3];
  const float* e1b = (const float*)d_in[4];
  const float* e2w = (const float*)d_in[5];
  const float* e2b = (const float*)d_in[6];
  const float* cw1 = (const float*)d_in[7];
  const float* cb1 = (const float*)d_in[8];
  const float* cw2 = (const float*)d_in[9];
  const float* cb2 = (const float*)d_in[10];
  const float* lw = (const float*)d_in[11];
  const float* lb = (const float*)d_in[12];
  const float* d1w = (const float*)d_in[13];
  const float* d1b = (const float*)d_in[14];
  const float* d2w = (const float*)d_in[15];
  const float* d2b = (const float*)d_in[16];

  const int N = in_sizes[0] / 4;
  const int E = in_sizes[2];
  const int* src = ei;
  const int* tgt = ei + E;

  char* p = (char*)d_ws;
  auto carve = [&](size_t bytes) -> char* {
    char* r = p;
    p += (bytes + 255) & ~(size_t)255;
    return r;
  };
  float* deg = (float*)carve((size_t)N * 4);  // becomes dis in place
  int* cur = (int*)carve((size_t)N * 4);      // cursor -> in-degree count
  unsigned long long* pair =
      (unsigned long long*)carve((size_t)N * PSTR * 8);
  __half* h16 = (__half*)carve((size_t)N * 64 * 2);
  __half* t16 = (__half*)carve((size_t)N * 64 * 2);
  __half* Tx16 = (__half*)carve((size_t)4 * N * 64 * 2);
  (void)ws_size;

  hipMemsetAsync(deg, 0, (size_t)N * 4, stream);
  hipMemsetAsync(cur, 0, (size_t)N * 4, stream);

  const int gE = (E + 255) / 256;
  const int gN = (N + 255) / 256;
  k_deg_fill<<<gE, 256, 0, stream>>>(src, tgt, ea, deg, cur, pair, E);
  k_dis<<<gN, 256, 0, stream>>>(deg, N);
  k_scale<<<(N + 3) / 4, 256, 0, stream>>>(deg, cur, pair, N);
  k_encode<<<2048, 256, 0, stream>>>(x, e1w, e1b, e2w, e2b, h16, N);

  const size_t n64 = (size_t)N * 64;
  const int gP = (N + 7) / 8;      // 4 waves/block, 2 nodes/wave
  const int gG = (N + 127) / 128;  // 128-row MFMA tiles
  __half* Tx1 = Tx16;
  __half* Tx2 = Tx16 + n64;
  __half* Tx3 = Tx16 + 2 * n64;
  __half* Tx4 = Tx16 + 3 * n64;
  for (int b = 0; b < 3; ++b) {
    const float* cw1b = cw1 + (size_t)b * 5 * 4096;
    const float* cb1b = cb1 + b * 64;
    const float* cw2b = cw2 + (size_t)b * 5 * 4096;
    const float* cb2b = cb2 + b * 64;
    const float* lwb = lw + (size_t)b * 4096;
    const float* lbb = lb + b * 64;

    // conv1: t16 = gelu(h@W0 + sum Tx_k@W_k + cb1)
    k_prop<false><<<gP, 256, 0, stream>>>(h16, cur, pair, nullptr, Tx1, N);
    k_prop<true><<<gP, 256, 0, stream>>>(Tx1, cur, pair, h16, Tx2, N);
    k_prop<true><<<gP, 256, 0, stream>>>(Tx2, cur, pair, Tx1, Tx3, N);
    k_prop<true><<<gP, 256, 0, stream>>>(Tx3, cur, pair, Tx2, Tx4, N);
    k_gemm_mfma<5, false, true><<<gG, 512, 0, stream>>>(
        h16, Tx16, cw1b, nullptr, nullptr, cb1b, nullptr, t16, N);

    // conv2 + residual: h16 = gelu(t@W0 + sum Ty_k@W_k + h@lw + cb2 + lb)
    k_prop<false><<<gP, 256, 0, stream>>>(t16, cur, pair, nullptr, Tx1, N);
    k_prop<true><<<gP, 256, 0, stream>>>(Tx1, cur, pair, t16, Tx2, N);
    k_prop<true><<<gP, 256, 0, stream>>>(Tx2, cur, pair, Tx1, Tx3, N);
    k_prop<true><<<gP, 256, 0, stream>>>(Tx3, cur, pair, Tx2, Tx4, N);
    k_gemm_mfma<6, true, true><<<gG, 512, 0, stream>>>(
        t16, Tx16, cw2b, h16, lwb, cb2b, lbb, h16, N);
  }

  const int gD = (int)(((size_t)N * 16 + 255) / 256);
  k_decode<<<gD, 256, 0, stream>>>(h16, d1w, d1b, d2w, d2b, (float*)d_out, N);
}